// Round 1
// baseline (737.251 us; speedup 1.0000x reference)
//
#include <hip/hip_runtime.h>

// WKV7 (RWKV-7) forward scan. T=2048, H=64, D=64.
// Layout: 512 blocks x 64 threads. Block = (head h, row-block br of 8 rows).
// Lane l: row = br*8 + (l>>3), columns [ (l&7)*8 , (l&7)*8+8 ).
// State S[row][8 cols] lives in 2x float4 registers per lane.
// Per-step column vectors (r, e^w, k, a, b) are loaded per-lane from global
// (double-buffered, prefetch distance 1). Row reductions via 3x shfl_xor
// among the 8 lanes of a row. No LDS, no barriers (1 wave per block).

constexpr int T_LEN = 2048;
constexpr int NH    = 64;
constexpr int DD    = 64;
constexpr int HD    = NH * DD;   // 4096

struct Buf {
  float4 r[2], e[2], k[2], a[2], b[2];
  float vv;
};

__global__ __launch_bounds__(256)
void exp_kernel(const float4* __restrict__ w, float4* __restrict__ ew, int n4) {
  int i = blockIdx.x * blockDim.x + threadIdx.x;
  int stride = gridDim.x * blockDim.x;
  for (; i < n4; i += stride) {
    float4 x = w[i];
    float4 o;
    o.x = __expf(x.x); o.y = __expf(x.y); o.z = __expf(x.z); o.w = __expf(x.w);
    ew[i] = o;
  }
}

template<bool INLINE_EXP>
__global__ __launch_bounds__(64)
void wkv7_scan(const float* __restrict__ R, const float* __restrict__ EW,
               const float* __restrict__ K, const float* __restrict__ V,
               const float* __restrict__ A, const float* __restrict__ B,
               const float* __restrict__ S0, float* __restrict__ X,
               float* __restrict__ SOUT)
{
  const int blk = blockIdx.x;          // 0..511
  // XCD-aware mapping: the 8 row-blocks of one head land on the same XCD
  // (assuming blk%8 -> XCD round robin) so their identical per-step vector
  // reads hit the same L2.
  const int xcd = blk & 7;
  const int m   = blk >> 3;            // 0..63
  const int h   = xcd * 8 + (m & 7);   // head 0..63
  const int br  = m >> 3;              // row block 0..7

  const int lane = threadIdx.x;        // 0..63
  const int cg   = lane & 7;           // column group (8 cols)
  const int rl   = lane >> 3;          // local row 0..7
  const int row  = br * 8 + rl;        // 0..63
  const int c0   = cg * 8;

  const int vecoff = h * DD + c0;      // per-step float offset for column vectors
  const int voff   = h * DD + row;     // per-step float offset for v / x

  float4 s[2];
  {
    const float4* sp = (const float4*)(S0 + (size_t)h * DD * DD + row * DD + c0);
    s[0] = sp[0]; s[1] = sp[1];
  }

  auto load = [&](Buf& bf, int t) {
    const size_t o = (size_t)t * HD + vecoff;
    const float4* r4 = (const float4*)(R  + o);
    const float4* e4 = (const float4*)(EW + o);
    const float4* k4 = (const float4*)(K  + o);
    const float4* a4 = (const float4*)(A  + o);
    const float4* b4 = (const float4*)(B  + o);
    bf.r[0] = r4[0]; bf.r[1] = r4[1];
    bf.e[0] = e4[0]; bf.e[1] = e4[1];
    bf.k[0] = k4[0]; bf.k[1] = k4[1];
    bf.a[0] = a4[0]; bf.a[1] = a4[1];
    bf.b[0] = b4[0]; bf.b[1] = b4[1];
    bf.vv = V[(size_t)t * HD + voff];
  };

  auto step = [&](const Buf& cur, int t) {
    float4 e0 = cur.e[0], e1 = cur.e[1];
    if (INLINE_EXP) {
      e0.x = __expf(e0.x); e0.y = __expf(e0.y);
      e0.z = __expf(e0.z); e0.w = __expf(e0.w);
      e1.x = __expf(e1.x); e1.y = __expf(e1.y);
      e1.z = __expf(e1.z); e1.w = __expf(e1.w);
    }
    // sa partial dot over this lane's 8 columns (2 accumulators)
    float p0, p1;
    p0 = s[0].x * cur.a[0].x;           p1 = s[0].y * cur.a[0].y;
    p0 = fmaf(s[0].z, cur.a[0].z, p0);  p1 = fmaf(s[0].w, cur.a[0].w, p1);
    p0 = fmaf(s[1].x, cur.a[1].x, p0);  p1 = fmaf(s[1].y, cur.a[1].y, p1);
    p0 = fmaf(s[1].z, cur.a[1].z, p0);  p1 = fmaf(s[1].w, cur.a[1].w, p1);
    float sa = p0 + p1;
    sa += __shfl_xor(sa, 1);
    sa += __shfl_xor(sa, 2);
    sa += __shfl_xor(sa, 4);

    const float vv = cur.vv;
    float y0 = 0.f, y1 = 0.f;

    s[0].x = fmaf(s[0].x, e0.x, fmaf(vv, cur.k[0].x, sa * cur.b[0].x));
    y0 = fmaf(s[0].x, cur.r[0].x, y0);
    s[0].y = fmaf(s[0].y, e0.y, fmaf(vv, cur.k[0].y, sa * cur.b[0].y));
    y1 = fmaf(s[0].y, cur.r[0].y, y1);
    s[0].z = fmaf(s[0].z, e0.z, fmaf(vv, cur.k[0].z, sa * cur.b[0].z));
    y0 = fmaf(s[0].z, cur.r[0].z, y0);
    s[0].w = fmaf(s[0].w, e0.w, fmaf(vv, cur.k[0].w, sa * cur.b[0].w));
    y1 = fmaf(s[0].w, cur.r[0].w, y1);

    s[1].x = fmaf(s[1].x, e1.x, fmaf(vv, cur.k[1].x, sa * cur.b[1].x));
    y0 = fmaf(s[1].x, cur.r[1].x, y0);
    s[1].y = fmaf(s[1].y, e1.y, fmaf(vv, cur.k[1].y, sa * cur.b[1].y));
    y1 = fmaf(s[1].y, cur.r[1].y, y1);
    s[1].z = fmaf(s[1].z, e1.z, fmaf(vv, cur.k[1].z, sa * cur.b[1].z));
    y0 = fmaf(s[1].z, cur.r[1].z, y0);
    s[1].w = fmaf(s[1].w, e1.w, fmaf(vv, cur.k[1].w, sa * cur.b[1].w));
    y1 = fmaf(s[1].w, cur.r[1].w, y1);

    float y = y0 + y1;
    y += __shfl_xor(y, 1);
    y += __shfl_xor(y, 2);
    y += __shfl_xor(y, 4);
    if (cg == 0) X[(size_t)t * HD + voff] = y;
  };

  Buf bA, bB;
  load(bA, 0);
  for (int t = 0; t < T_LEN; t += 2) {
    load(bB, t + 1);
    step(bA, t);
    load(bA, (t + 2 < T_LEN) ? (t + 2) : 0);  // harmless dummy reload on last iter
    step(bB, t + 1);
  }

  float4* so = (float4*)(SOUT + (size_t)h * DD * DD + row * DD + c0);
  so[0] = s[0]; so[1] = s[1];
}

extern "C" void kernel_launch(void* const* d_in, const int* in_sizes, int n_in,
                              void* d_out, int out_size, void* d_ws, size_t ws_size,
                              hipStream_t stream) {
  // setup_inputs order: seq_length, r, w, k, v, a, b, state2
  const float* r  = (const float*)d_in[1];
  const float* w  = (const float*)d_in[2];
  const float* k  = (const float*)d_in[3];
  const float* v  = (const float*)d_in[4];
  const float* a  = (const float*)d_in[5];
  const float* b  = (const float*)d_in[6];
  const float* s0 = (const float*)d_in[7];

  float* x    = (float*)d_out;                     // (T, H, 1, D)
  float* sout = x + (size_t)T_LEN * HD;            // (H, D, D)

  const size_t ew_bytes = (size_t)T_LEN * HD * sizeof(float);
  if (ws_size >= ew_bytes) {
    float* ew = (float*)d_ws;
    int n4 = T_LEN * HD / 4;
    hipLaunchKernelGGL(exp_kernel, dim3(1024), dim3(256), 0, stream,
                       (const float4*)w, (float4*)ew, n4);
    hipLaunchKernelGGL((wkv7_scan<false>), dim3(512), dim3(64), 0, stream,
                       r, ew, k, v, a, b, s0, x, sout);
  } else {
    hipLaunchKernelGGL((wkv7_scan<true>), dim3(512), dim3(64), 0, stream,
                       r, w, k, v, a, b, s0, x, sout);
  }
}

// Round 2
// 360.066 us; speedup vs baseline: 2.0475x; 2.0475x over previous
//
#include <hip/hip_runtime.h>

// WKV7 (RWKV-7) forward scan. T=2048, H=64, D=64.
// R2: 1024 blocks x 64 threads. Block = (head h, row-block br of 4 rows).
// Lane l: rl = l>>4 (local row 0..3), cg = l&15, owns cols [cg*4, cg*4+4).
// State = float4 per lane. Row reductions = 4 DPP adds (no LDS, no ds_swizzle).
// Prefetch distance 4 via 8 static-named buffers, unroll-8 loop.

constexpr int T_LEN = 2048;
constexpr int DD    = 64;
constexpr int HD    = 64 * 64;   // 4096

struct Buf {
  float4 r, e, k, a, b;
  float vv;
};

__global__ __launch_bounds__(256)
void exp_kernel(const float4* __restrict__ w, float4* __restrict__ ew, int n4) {
  int i = blockIdx.x * blockDim.x + threadIdx.x;
  int stride = gridDim.x * blockDim.x;
  for (; i < n4; i += stride) {
    float4 x = w[i];
    float4 o;
    o.x = __expf(x.x); o.y = __expf(x.y); o.z = __expf(x.z); o.w = __expf(x.w);
    ew[i] = o;
  }
}

template<int CTRL>
__device__ __forceinline__ float dpp_add(float x) {
  int y = __builtin_amdgcn_update_dpp(0, __float_as_int(x), CTRL, 0xf, 0xf, true);
  return x + __int_as_float(y);
}

// Sum across the 16 lanes of a DPP row (all lanes end with the sum).
__device__ __forceinline__ float row16_reduce(float x) {
  x = dpp_add<0xB1>(x);    // quad_perm [1,0,3,2] : + lane^1
  x = dpp_add<0x4E>(x);    // quad_perm [2,3,0,1] : + lane^2
  x = dpp_add<0x141>(x);   // row_half_mirror    : + other quad (quad-uniform)
  x = dpp_add<0x140>(x);   // row_mirror         : + other half (half-uniform)
  return x;
}

__global__ __launch_bounds__(64)
void wkv7_scan(const float* __restrict__ R, const float* __restrict__ EW,
               const float* __restrict__ K, const float* __restrict__ V,
               const float* __restrict__ A, const float* __restrict__ B,
               const float* __restrict__ S0, float* __restrict__ X,
               float* __restrict__ SOUT)
{
  const int blk = blockIdx.x;          // 0..1023
  // XCD co-location heuristic: blockIdx round-robins XCDs, so give each XCD
  // 8 whole heads (16 row-blocks each) for L2 reuse of the per-step vectors.
  const int xcd = blk & 7;
  const int m   = blk >> 3;            // 0..127
  const int h   = xcd * 8 + (m & 7);   // head 0..63
  const int br  = m >> 3;              // row block 0..15

  const int lane = threadIdx.x;        // 0..63
  const int cg   = lane & 15;          // column group -> cols [cg*4, cg*4+4)
  const int rl   = lane >> 4;          // local row 0..3
  const int row  = br * 4 + rl;        // 0..63
  const int c0   = cg * 4;

  const int vecoff = h * DD + c0;      // float offset for per-step column vectors
  const int voff   = h * DD + row;     // float offset for v / x

  const float* Rp = R  + vecoff;
  const float* Ep = EW + vecoff;
  const float* Kp = K  + vecoff;
  const float* Ap = A  + vecoff;
  const float* Bp = B  + vecoff;
  const float* Vp = V  + voff;
  float*       Xp = X  + voff;

  float4 s = *(const float4*)(S0 + (size_t)h * DD * DD + row * DD + c0);

  auto load = [&](Buf& bf, int t) {
    const size_t o = (size_t)t * HD;
    bf.r  = *(const float4*)(Rp + o);
    bf.e  = *(const float4*)(Ep + o);
    bf.k  = *(const float4*)(Kp + o);
    bf.a  = *(const float4*)(Ap + o);
    bf.b  = *(const float4*)(Bp + o);
    bf.vv = Vp[o];
  };

  auto step = [&](const Buf& c, int t) {
    // sa partial over this lane's 4 cols (2 independent chains, depth 2)
    float p0 = fmaf(s.z, c.a.z, s.x * c.a.x);
    float p1 = fmaf(s.w, c.a.w, s.y * c.a.y);
    float sa = row16_reduce(p0 + p1);

    const float vv = c.vv;
    s.x = fmaf(s.x, c.e.x, fmaf(vv, c.k.x, sa * c.b.x));
    s.y = fmaf(s.y, c.e.y, fmaf(vv, c.k.y, sa * c.b.y));
    s.z = fmaf(s.z, c.e.z, fmaf(vv, c.k.z, sa * c.b.z));
    s.w = fmaf(s.w, c.e.w, fmaf(vv, c.k.w, sa * c.b.w));

    float y0 = fmaf(s.z, c.r.z, s.x * c.r.x);
    float y1 = fmaf(s.w, c.r.w, s.y * c.r.y);
    float y  = row16_reduce(y0 + y1);
    // all 16 lanes of this row group write the same value to the same address
    // (one store instruction, no exec-mask manipulation; HW picks a winner).
    Xp[(size_t)t * HD] = y;
  };

  Buf A0, A1, A2, A3, B0, B1, B2, B3;
  load(A0, 0); load(A1, 1); load(A2, 2); load(A3, 3);

  for (int t = 0; t < T_LEN; t += 8) {
    load(B0, (t + 4) & (T_LEN - 1));  step(A0, t);
    load(B1, (t + 5) & (T_LEN - 1));  step(A1, t + 1);
    load(B2, (t + 6) & (T_LEN - 1));  step(A2, t + 2);
    load(B3, (t + 7) & (T_LEN - 1));  step(A3, t + 3);
    load(A0, (t + 8) & (T_LEN - 1));  step(B0, t + 4);
    load(A1, (t + 9) & (T_LEN - 1));  step(B1, t + 5);
    load(A2, (t + 10) & (T_LEN - 1)); step(B2, t + 6);
    load(A3, (t + 11) & (T_LEN - 1)); step(B3, t + 7);
  }

  *(float4*)(SOUT + (size_t)h * DD * DD + row * DD + c0) = s;
}

extern "C" void kernel_launch(void* const* d_in, const int* in_sizes, int n_in,
                              void* d_out, int out_size, void* d_ws, size_t ws_size,
                              hipStream_t stream) {
  // setup_inputs order: seq_length, r, w, k, v, a, b, state2
  const float* r  = (const float*)d_in[1];
  const float* w  = (const float*)d_in[2];
  const float* k  = (const float*)d_in[3];
  const float* v  = (const float*)d_in[4];
  const float* a  = (const float*)d_in[5];
  const float* b  = (const float*)d_in[6];
  const float* s0 = (const float*)d_in[7];

  float* x    = (float*)d_out;                     // (T, H, 1, D)
  float* sout = x + (size_t)T_LEN * HD;            // (H, D, D)

  const size_t ew_bytes = (size_t)T_LEN * HD * sizeof(float);
  float* ew = (float*)d_ws;
  (void)ws_size; (void)in_sizes; (void)n_in; (void)ew_bytes;

  int n4 = T_LEN * HD / 4;
  hipLaunchKernelGGL(exp_kernel, dim3(1024), dim3(256), 0, stream,
                     (const float4*)w, (float4*)ew, n4);
  hipLaunchKernelGGL(wkv7_scan, dim3(1024), dim3(64), 0, stream,
                     r, ew, k, v, a, b, s0, x, sout);
}